// Round 2
// baseline (122.444 us; speedup 1.0000x reference)
//
#include <hip/hip_runtime.h>

#define DEV __device__ __forceinline__

typedef __attribute__((ext_vector_type(8))) short bf16x8;
typedef __attribute__((ext_vector_type(4))) short bf16x4;
typedef __attribute__((ext_vector_type(4))) float f32x4;
typedef __attribute__((ext_vector_type(4))) unsigned int u32x4;

constexpr int Bb = 8;
constexpr int Nn = 1024;
constexpr int DIMm = 512;
constexpr int Hh = 8;
constexpr int Dh = 64;
constexpr int Mm = Bb * Nn;  // 8192
constexpr float LN10K = 9.210340371976184f;   // ln(10000)
constexpr float LOG2E = 1.4426950408889634f;  // log2(e)

DEV short f2bf(float f) {
  unsigned int u = __float_as_uint(f);
  u += 0x7fffu + ((u >> 16) & 1u);  // RNE
  return (short)(u >> 16);
}

DEV unsigned int cvtpk(float lo, float hi) {  // dword = {bf16(lo), bf16(hi)}
  unsigned int r;
  asm("v_cvt_pk_bf16_f32 %0, %1, %2" : "=v"(r) : "v"(lo), "v"(hi));
  return r;
}

DEV bf16x8 comb(bf16x4 lo, bf16x4 hi) {
  bf16x8 r;
  r[0] = lo[0]; r[1] = lo[1]; r[2] = lo[2]; r[3] = lo[3];
  r[4] = hi[0]; r[5] = hi[1]; r[6] = hi[2]; r[7] = hi[3];
  return r;
}

DEV f32x4 mfma16(bf16x8 a, bf16x8 b, f32x4 c) {
  return __builtin_amdgcn_mfma_f32_16x16x32_bf16(a, b, c, 0, 0, 0);
}

DEV void gload16(const void* g, void* l) {
  __builtin_amdgcn_global_load_lds(
      (const __attribute__((address_space(1))) void*)g,
      (__attribute__((address_space(3))) void*)l, 16, 0, 0);
}

// ---------------------------------------------------------------------------
// prep: x -> bf16 ; w_qkv -> transposed bf16 [1536][512] ; w_out -> [512][512];
// RoPE cos/sin table [N][32] float2
// ---------------------------------------------------------------------------
__global__ void prep_kernel(const float* __restrict__ x, const float* __restrict__ wq,
                            const float* __restrict__ wo, short* __restrict__ x_bf,
                            short* __restrict__ wqkvT, short* __restrict__ woutT,
                            float2* __restrict__ tab) {
  int stride = gridDim.x * blockDim.x;
  int t = blockIdx.x * blockDim.x + threadIdx.x;
  for (int i = t; i < Mm * DIMm / 4; i += stride) {
    float4 v = ((const float4*)x)[i];
    bf16x4 o;
    o[0] = f2bf(v.x); o[1] = f2bf(v.y); o[2] = f2bf(v.z); o[3] = f2bf(v.w);
    *(bf16x4*)(x_bf + (size_t)i * 4) = o;
  }
  for (int i = t; i < 1536 * 512; i += stride) {
    int n = i >> 9, k = i & 511;
    wqkvT[i] = f2bf(wq[(size_t)k * 1536 + n]);
  }
  for (int i = t; i < 512 * 512; i += stride) {
    int n = i >> 9, k = i & 511;
    woutT[i] = f2bf(wo[(size_t)k * 512 + n]);
  }
  for (int i = t; i < Nn * 32; i += stride) {
    int n = i >> 5, d2 = i & 31;
    float fr = (float)n * __expf(-(float)(2 * d2) * (LN10K / 64.f));
    float sn, cs;
    __sincosf(fr, &sn, &cs);
    tab[i] = make_float2(cs, sn);
  }
}

// ---------------------------------------------------------------------------
// GEMM: A[Mx512] bf16 row-major, Bt[Ncols x 512] bf16 (pre-transposed).
// QKV==1: epilogue applies RoPE (table) + q-scale(0.125*log2e), writes
//         qr/kr [b][h][n][d], vt [b][h][d][n].   QKV==0: f32 store.
// ---------------------------------------------------------------------------
template <int QKV>
__global__ __launch_bounds__(256) void gemm_k(const short* __restrict__ A,
                                              const short* __restrict__ Bt,
                                              float* __restrict__ outF,
                                              short* __restrict__ qr,
                                              short* __restrict__ kr,
                                              short* __restrict__ vt,
                                              const float2* __restrict__ tab) {
  __shared__ short Al[128][40];
  __shared__ short Bl[128][40];
  const int tid = threadIdx.x;
  const int lane = tid & 63;
  const int wid = tid >> 6;
  const int wm = wid >> 1, wn = wid & 1;
  const int li = lane & 15, g4 = (lane >> 4) << 2;
  const int m0 = blockIdx.x * 128, n0 = blockIdx.y * 128;

  f32x4 zero4 = {0.f, 0.f, 0.f, 0.f};
  f32x4 acc[4][4];
#pragma unroll
  for (int i = 0; i < 4; ++i)
#pragma unroll
    for (int j = 0; j < 4; ++j) acc[i][j] = zero4;

  for (int kt = 0; kt < 512; kt += 32) {
#pragma unroll
    for (int p = 0; p < 2; ++p) {
      int e = (tid + p * 256) * 8;
      int r = e >> 5, c = e & 31;
      *(u32x4*)(&Al[r][c]) = *(const u32x4*)(A + (size_t)(m0 + r) * 512 + kt + c);
      *(u32x4*)(&Bl[r][c]) = *(const u32x4*)(Bt + (size_t)(n0 + r) * 512 + kt + c);
    }
    __syncthreads();
    bf16x8 af[4], bfr[4];
#pragma unroll
    for (int mt = 0; mt < 4; ++mt) {
      int row = wm * 64 + mt * 16 + li;
      af[mt] = comb(*(const bf16x4*)(&Al[row][g4]), *(const bf16x4*)(&Al[row][16 + g4]));
    }
#pragma unroll
    for (int nt = 0; nt < 4; ++nt) {
      int row = wn * 64 + nt * 16 + li;
      bfr[nt] = comb(*(const bf16x4*)(&Bl[row][g4]), *(const bf16x4*)(&Bl[row][16 + g4]));
    }
#pragma unroll
    for (int mt = 0; mt < 4; ++mt)
#pragma unroll
      for (int nt = 0; nt < 4; ++nt)
        acc[mt][nt] = mfma16(af[mt], bfr[nt], acc[mt][nt]);
    __syncthreads();
  }

  if (QKV == 0) {
#pragma unroll
    for (int mt = 0; mt < 4; ++mt) {
      int mb = m0 + wm * 64 + mt * 16 + g4;
#pragma unroll
      for (int nt = 0; nt < 4; ++nt) {
        int c = n0 + wn * 64 + nt * 16 + li;
#pragma unroll
        for (int r = 0; r < 4; ++r) outF[(size_t)(mb + r) * 512 + c] = acc[mt][nt][r];
      }
    }
  } else {
    const int sec = n0 >> 9;  // 0=q 1=k 2=v
#pragma unroll
    for (int mt = 0; mt < 4; ++mt) {
      int mb = m0 + wm * 64 + mt * 16 + g4;
      int b_ = mb >> 10;
      int nb = mb & 1023;
#pragma unroll
      for (int nt = 0; nt < 4; ++nt) {
        int c = n0 + wn * 64 + nt * 16 + li;
        int cs = c & 511;
        int hh = cs >> 6, d = cs & 63;
        if (sec == 2) {
          uint2 st;
          st.x = cvtpk(acc[mt][nt][0], acc[mt][nt][1]);
          st.y = cvtpk(acc[mt][nt][2], acc[mt][nt][3]);
          *(uint2*)(vt + ((size_t)(b_ * Hh + hh) * Dh + d) * Nn + nb) = st;
        } else {
          short* dst = (sec == 0 ? qr : kr) + ((size_t)(b_ * Hh + hh) * Nn + nb) * Dh + d;
#pragma unroll
          for (int r = 0; r < 4; ++r) {
            float v0 = acc[mt][nt][r];
            float vp = __shfl_xor(v0, 1, 64);  // RoPE pair partner
            float2 cssn = tab[(size_t)(nb + r) * 32 + (d >> 1)];
            float rot = (d & 1) ? vp : -vp;
            float res = v0 * cssn.x + rot * cssn.y;
            if (sec == 0) res *= 0.125f * LOG2E;  // Dh^-0.5, log2-domain fold
            dst[(size_t)r * Dh] = f2bf(res);
          }
        }
      }
    }
  }
}

// ---------------------------------------------------------------------------
// Flash attention (swapped-QK S^T trick), KVBLK=128, exp2-domain softmax,
// XOR-swizzled LDS staged via global_load_lds(16B) with pre-swizzled source.
// 4 waves x 16 q-rows = 64 q-rows per block.
// ---------------------------------------------------------------------------
__global__ __launch_bounds__(256, 4) void attn_k(const short* __restrict__ qr,
                                                 const short* __restrict__ kr,
                                                 const short* __restrict__ vt,
                                                 const float* __restrict__ bias,
                                                 short* __restrict__ ao) {
  __shared__ short Kl[128 * 64];   // rows of 64 shorts (128 B), XOR-swizzled
  __shared__ short Vl[64 * 128];   // rows of 128 shorts (256 B), XOR-swizzled
  const int tid = threadIdx.x, lane = tid & 63, w = tid >> 6;
  const int li = lane & 15, g4 = (lane >> 4) << 2;
  // XCD swizzle: each XCD owns one head (bias/head = 4MB ~ L2)
  const int bid = blockIdx.x;
  const int h = bid & 7;
  const int inner = bid >> 3;
  const int b_ = inner >> 4, it = inner & 15;
  const int bh = b_ * 8 + h;
  const int i0 = it * 64;
  const int iq = i0 + w * 16 + li;

  const short* qrow = qr + ((size_t)bh * Nn + iq) * Dh;
  bf16x8 qf[2];
#pragma unroll
  for (int kk = 0; kk < 2; ++kk)
    qf[kk] = comb(*(const bf16x4*)(qrow + kk * 32 + g4),
                  *(const bf16x4*)(qrow + kk * 32 + 16 + g4));

  const char* KbB = (const char*)(kr + (size_t)bh * Nn * Dh);
  const char* VbB = (const char*)(vt + (size_t)bh * Dh * Nn);
  const float* brow = bias + ((size_t)h * Nn + iq) * Nn;

  float m_run = -1e30f, l_run = 0.f;
  f32x4 zero4 = {0.f, 0.f, 0.f, 0.f};
  f32x4 acc[4];
#pragma unroll
  for (int i = 0; i < 4; ++i) acc[i] = zero4;

  for (int j0 = 0; j0 < Nn; j0 += 128) {
    f32x4 bb[8];
#pragma unroll
    for (int js = 0; js < 8; ++js)
      bb[js] = *(const f32x4*)(brow + j0 + js * 16 + g4);

    __syncthreads();  // WAR: prev tile's LDS reads done
#pragma unroll
    for (int p = 0; p < 4; ++p) {
      // K region: 16 KB, logical row = 128 B
      int L = (tid + p * 256) * 16;
      int row = L >> 7, sb = L & 127;
      int gb = sb ^ ((row & 7) << 4);
      gload16(KbB + (size_t)(j0 + row) * 128 + gb, (char*)Kl + L);
      // V region: 16 KB, logical row = 256 B (row = d, col = j)
      int rv = L >> 8, sv = L & 255;
      int gv = sv ^ ((rv & 7) << 4);
      gload16(VbB + (size_t)rv * 2048 + (size_t)j0 * 2 + gv, (char*)Vl + L);
    }
    __syncthreads();  // vmcnt(0): tiles ready

    // S^T: lane holds q-row i=li, j = js*16 + g4 + r ; C-init = bias*log2e
    f32x4 s[8];
#pragma unroll
    for (int js = 0; js < 8; ++js) {
      int row = js * 16 + li;
      int sw = (row & 7) << 3;  // short-index swizzle
      const short* kb = Kl + row * 64;
      f32x4 sa = bb[js] * LOG2E;
      bf16x8 kf0 = comb(*(const bf16x4*)(kb + ((g4) ^ sw)),
                        *(const bf16x4*)(kb + ((16 + g4) ^ sw)));
      bf16x8 kf1 = comb(*(const bf16x4*)(kb + ((32 + g4) ^ sw)),
                        *(const bf16x4*)(kb + ((48 + g4) ^ sw)));
      sa = mfma16(kf0, qf[0], sa);
      sa = mfma16(kf1, qf[1], sa);
      s[js] = sa;
    }

    // row max (log2 domain)
    float mx = -3e38f;
#pragma unroll
    for (int js = 0; js < 8; ++js) {
      float a = fmaxf(fmaxf(s[js][0], s[js][1]), fmaxf(s[js][2], s[js][3]));
      mx = fmaxf(mx, a);
    }
    mx = fmaxf(mx, __shfl_xor(mx, 16, 64));
    mx = fmaxf(mx, __shfl_xor(mx, 32, 64));

    // defer-max: rescale only when max grew past threshold
    if (!__all(mx - m_run <= 8.0f)) {
      float mn = fmaxf(m_run, mx);
      float sc = __builtin_amdgcn_exp2f(m_run - mn);
      l_run *= sc;
      m_run = mn;
      float fs0 = __shfl(sc, g4 + 0, 64), fs1 = __shfl(sc, g4 + 1, 64);
      float fs2 = __shfl(sc, g4 + 2, 64), fs3 = __shfl(sc, g4 + 3, 64);
#pragma unroll
      for (int dt = 0; dt < 4; ++dt) {
        acc[dt][0] *= fs0; acc[dt][1] *= fs1;
        acc[dt][2] *= fs2; acc[dt][3] *= fs3;
      }
    }

    float rs = 0.f;
#pragma unroll
    for (int js = 0; js < 8; ++js)
#pragma unroll
      for (int r = 0; r < 4; ++r) {
        float p = __builtin_amdgcn_exp2f(s[js][r] - m_run);
        s[js][r] = p;
        rs += p;
      }
    rs += __shfl_xor(rs, 16, 64);
    rs += __shfl_xor(rs, 32, 64);
    l_run += rs;

    // P -> bf16 A-frags: pf[kk] covers j in [32kk, 32kk+32)
    bf16x8 pf[4];
#pragma unroll
    for (int kk = 0; kk < 4; ++kk) {
      union { bf16x8 v; unsigned int d[4]; } u;
      u.d[0] = cvtpk(s[2 * kk][0], s[2 * kk][1]);
      u.d[1] = cvtpk(s[2 * kk][2], s[2 * kk][3]);
      u.d[2] = cvtpk(s[2 * kk + 1][0], s[2 * kk + 1][1]);
      u.d[3] = cvtpk(s[2 * kk + 1][2], s[2 * kk + 1][3]);
      pf[kk] = u.v;
    }

    // PV: acc[dt] rows = q-rows, cols = d = dt*16+li
#pragma unroll
    for (int dt = 0; dt < 4; ++dt) {
      int row = dt * 16 + li;
      int sw = (row & 7) << 3;
      const short* vb = Vl + row * 128;
#pragma unroll
      for (int kk = 0; kk < 4; ++kk) {
        int c = kk * 32 + g4;
        bf16x8 vf = comb(*(const bf16x4*)(vb + (c ^ sw)),
                         *(const bf16x4*)(vb + ((c + 16) ^ sw)));
        acc[dt] = mfma16(pf[kk], vf, acc[dt]);
      }
    }
  }

  float rl = 1.f / l_run;
  float fr0 = __shfl(rl, g4 + 0, 64), fr1 = __shfl(rl, g4 + 1, 64);
  float fr2 = __shfl(rl, g4 + 2, 64), fr3 = __shfl(rl, g4 + 3, 64);
#pragma unroll
  for (int dt = 0; dt < 4; ++dt) {
    float fr[4] = {fr0, fr1, fr2, fr3};
#pragma unroll
    for (int r = 0; r < 4; ++r) {
      int i_ = i0 + w * 16 + g4 + r;
      ao[((size_t)(b_ * Nn + i_)) * 512 + h * 64 + dt * 16 + li] =
          f2bf(acc[dt][r] * fr[r]);
    }
  }
}

// ---------------------------------------------------------------------------
extern "C" void kernel_launch(void* const* d_in, const int* in_sizes, int n_in,
                              void* d_out, int out_size, void* d_ws, size_t ws_size,
                              hipStream_t stream) {
  const float* x = (const float*)d_in[0];
  const float* pb = (const float*)d_in[1];
  const float* wq = (const float*)d_in[2];
  const float* wo = (const float*)d_in[3];
  float* out = (float*)d_out;

  short* w = (short*)d_ws;
  short* x_bf = w;  w += (size_t)Mm * DIMm;      // 8 MB
  short* wqkvT = w; w += 1536 * 512;             // 1.5 MB
  short* woutT = w; w += 512 * 512;              // 0.5 MB
  short* qr = w;    w += (size_t)Mm * DIMm;      // 8 MB
  short* kr = w;    w += (size_t)Mm * DIMm;      // 8 MB
  short* vt = w;    w += (size_t)Mm * DIMm;      // 8 MB
  float2* tab = (float2*)w; w += Nn * 32 * 4;    // 256 KB
  short* ao = x_bf;  // x_bf dead after qkv GEMM

  prep_kernel<<<1024, 256, 0, stream>>>(x, wq, wo, x_bf, wqkvT, woutT, tab);
  gemm_k<1><<<dim3(64, 12), 256, 0, stream>>>(x_bf, wqkvT, nullptr, qr, kr, vt, tab);
  attn_k<<<1024, 256, 0, stream>>>(qr, kr, vt, pb, ao);
  gemm_k<0><<<dim3(64, 4), 256, 0, stream>>>(ao, woutT, out, nullptr, nullptr, nullptr, tab);
}